// Round 10
// baseline (1334.543 us; speedup 1.0000x reference)
//
#include <hip/hip_runtime.h>

typedef unsigned long long ULL;

// B=8, Cin=Cout=256, H=W=64, A=9, N=36864/batch, PRE=1000, POST=300

__device__ __forceinline__ ULL fkey64(double f) {
    ULL u = (ULL)__double_as_longlong(f);
    return (u & 0x8000000000000000ull) ? ~u : (u | 0x8000000000000000ull);
}

// ---------------- kernel 1: prep (merged): wt64 transpose->fp64 + clf diff weights ----------
__global__ void prep_all(const float* __restrict__ wconv,
                         const float* __restrict__ wclf, const float* __restrict__ bclf,
                         double* __restrict__ wt64,
                         double* __restrict__ wdiff, double* __restrict__ bdiff) {
    int blk = blockIdx.x;
    if (blk < 2304) {
        int e = blk * 256 + threadIdx.x;   // 589824 total
        int row = e >> 8;                  // ci*9 + tap
        int co = e & 255;
        int ci = row / 9;
        int tap = row - ci * 9;
        wt64[e] = (double)wconv[(co * 256 + ci) * 9 + tap];
    } else {
        int a = blk - 2304;                // 0..8
        int c = threadIdx.x;
        wdiff[a * 256 + c] = (double)wclf[(9 + a) * 256 + c] - (double)wclf[a * 256 + c];
        if (c == 0) bdiff[a] = (double)bclf[9 + a] - (double)bclf[a];
    }
}

// ---------------- kernel 2: 3x3 conv + bias + relu, fp64 dfma, 8px x 8co per thread ---------
// grid 512 = 8 b * 32 rowpairs * 2 cogroups; block 256; tile 128 px (2 rows) x 128 co.
// w staged via REGISTER prefetch -> LDS fp64 (r3-proven pattern; NO global_load_lds — r7's
// failing variant differed from proven configs only by glds@2blk/CU). LDS-bound analysis:
// 4px tile = 168 LDS instr / 1152 dfma (LDS 32K cyc vs fp64 18K -> 847us); 8px tile =
// ~194 LDS instr / 2304 dfma -> balanced ~18.5K cyc -> ~600us. Summation order per output
// pixel is bitwise identical to the r5/r9 conv.
// VGPR: acc 128 + wreg 36 + xd 20 + temps ~30 = ~215 < 256 cap at (256,2) -> no spill.
__global__ __launch_bounds__(256, 2) void conv3x3_relu_f64(
    const float* __restrict__ xin, const double* __restrict__ wt64,
    const float* __restrict__ bias, double* __restrict__ y)
{
    __shared__ double wsd[4608];   // [k 0..35][co 0..127] for this cog (d2 idx = k*64+c2)
    __shared__ float xs[1152];     // [cil 0..3][row 0..3][72]; col c holds input col c-1

    const int t = threadIdx.x;
    const int blk = blockIdx.x;
    const int b = blk >> 6;
    const int rp = (blk >> 1) & 31;
    const int cog = blk & 1;
    const int h0 = rp * 2;
    const int tx = t & 15, ty = t >> 4;
    const int r = tx >> 3;                 // output row within pair
    const int colbase = (tx & 7) * 8;      // 8 consecutive output cols

    double acc[8][8];                      // [co][px]
#pragma unroll
    for (int i = 0; i < 8; i++)
#pragma unroll
        for (int j = 0; j < 8; j++) acc[i][j] = 0.0;

    // x staging decomposition: 4 cil * 4 rows (h0-1..h0+2) * 66 cols = 1056 elems
    int x_ld[5], x_go[5];
#pragma unroll
    for (int i = 0; i < 5; i++) {
        int e = t + i * 256;
        x_ld[i] = -1; x_go[i] = -1;
        if (e < 1056) {
            int cil = e / 264; int rem = e - cil * 264;
            int row = rem / 66; int c = rem - row * 66;
            int hh = h0 - 1 + row; int col = c - 1;
            x_ld[i] = (cil * 4 + row) * 72 + c;
            if (hh >= 0 && hh < 64 && col >= 0 && col < 64)
                x_go[i] = cil * 4096 + hh * 64 + col;
        }
    }
    // w: 2304 double2 per chunk; e2 = t + i*256; k = e2>>6, c2 = e2&63
    // global d2 (chunk-rel) = k*128 + cog*64 + c2 = e2 + (e2>>6)*64 + cog*64
    int w_g[9];
#pragma unroll
    for (int i = 0; i < 9; i++) {
        int e2 = t + i * 256;
        w_g[i] = e2 + (e2 >> 6) * 64 + cog * 64;
    }

    const float* xb = xin + (size_t)b * 1048576;
    const double2* wt2 = (const double2*)wt64;
    double2* wsd2 = (double2*)wsd;

    // preload chunk 0 into regs
    float xreg[5];
    double2 wreg[9];
#pragma unroll
    for (int i = 0; i < 5; i++)
        xreg[i] = (x_ld[i] >= 0 && x_go[i] >= 0) ? xb[x_go[i]] : 0.f;
#pragma unroll
    for (int i = 0; i < 9; i++) wreg[i] = wt2[w_g[i]];

    for (int cc = 0; cc < 64; ++cc) {
        __syncthreads();   // previous compute done before LDS overwrite
#pragma unroll
        for (int i = 0; i < 5; i++) if (x_ld[i] >= 0) xs[x_ld[i]] = xreg[i];
#pragma unroll
        for (int i = 0; i < 9; i++) wsd2[t + i * 256] = wreg[i];
        __syncthreads();

        // prefetch next chunk into regs (overlaps with compute below)
        if (cc < 63) {
#pragma unroll
            for (int i = 0; i < 5; i++)
                if (x_ld[i] >= 0)
                    xreg[i] = (x_go[i] >= 0) ? xb[(cc + 1) * 16384 + x_go[i]] : 0.f;
#pragma unroll
            for (int i = 0; i < 9; i++)
                wreg[i] = wt2[(size_t)(cc + 1) * 4608 + w_g[i]];
        }

#pragma unroll
        for (int cil = 0; cil < 4; cil++) {
#pragma unroll
            for (int kh = 0; kh < 3; kh++) {
                const float* xrow = &xs[(cil * 4 + r + kh) * 72 + colbase];
                float4 xa = *(const float4*)xrow;
                float4 xb4 = *(const float4*)(xrow + 4);
                float2 xc2 = *(const float2*)(xrow + 8);
                double xd[10] = { (double)xa.x, (double)xa.y, (double)xa.z, (double)xa.w,
                                  (double)xb4.x, (double)xb4.y, (double)xb4.z, (double)xb4.w,
                                  (double)xc2.x, (double)xc2.y };
#pragma unroll
                for (int kw = 0; kw < 3; kw++) {
                    int k = cil * 9 + kh * 3 + kw;
                    const double2* wp = (const double2*)wsd + (k * 64 + ty * 4);
                    double2 w01 = wp[0], w23 = wp[1], w45 = wp[2], w67 = wp[3];
#pragma unroll
                    for (int j = 0; j < 8; j++) {
                        double xv = xd[j + kw];
                        acc[0][j] = fma(w01.x, xv, acc[0][j]);
                        acc[1][j] = fma(w01.y, xv, acc[1][j]);
                        acc[2][j] = fma(w23.x, xv, acc[2][j]);
                        acc[3][j] = fma(w23.y, xv, acc[3][j]);
                        acc[4][j] = fma(w45.x, xv, acc[4][j]);
                        acc[5][j] = fma(w45.y, xv, acc[5][j]);
                        acc[6][j] = fma(w67.x, xv, acc[6][j]);
                        acc[7][j] = fma(w67.y, xv, acc[7][j]);
                    }
                }
            }
        }
    }

    // epilogue: bias + relu (fp64), store NHWC fp64
    const float* bptr = bias + cog * 128 + ty * 8;
    double bs[8];
#pragma unroll
    for (int i = 0; i < 8; i++) bs[i] = (double)bptr[i];
    const int h = h0 + r;
    double* yb = y + ((size_t)(b * 4096 + h * 64 + colbase)) * 256 + cog * 128 + ty * 8;
#pragma unroll
    for (int j = 0; j < 8; j++) {
        double4 o0, o1;
        o0.x = fmax(acc[0][j] + bs[0], 0.0);
        o0.y = fmax(acc[1][j] + bs[1], 0.0);
        o0.z = fmax(acc[2][j] + bs[2], 0.0);
        o0.w = fmax(acc[3][j] + bs[3], 0.0);
        o1.x = fmax(acc[4][j] + bs[4], 0.0);
        o1.y = fmax(acc[5][j] + bs[5], 0.0);
        o1.z = fmax(acc[6][j] + bs[6], 0.0);
        o1.w = fmax(acc[7][j] + bs[7], 0.0);
        double* yp = yb + (size_t)j * 256;
        *(double4*)yp = o0;
        *((double4*)yp + 1) = o1;
    }
}

// ---------------- kernel 3: clf head via fp64 diff-weights; thread = (pixel, anchor) ---------
__global__ __launch_bounds__(256) void head_clf2(
    const double* __restrict__ y, const double* __restrict__ wdiff,
    const double* __restrict__ bdiff, double* __restrict__ dlog)
{
    __shared__ double wd[9 * 258];   // padded stride 258 (bank spread)
    __shared__ double bd[9];
    for (int i = threadIdx.x; i < 9 * 258; i += 256) {
        int a = i / 258, c = i - a * 258;
        wd[i] = (c < 256) ? wdiff[a * 256 + c] : 0.0;
    }
    if (threadIdx.x < 9) bd[threadIdx.x] = bdiff[threadIdx.x];
    __syncthreads();

    int gid = blockIdx.x * 256 + threadIdx.x;    // 0..294911
    int px = gid / 9;
    int a = gid - px * 9;
    const double2* y2 = (const double2*)(y + (size_t)px * 256);
    const double2* w2 = (const double2*)(wd + a * 258);
    double s0 = 0.0, s1 = 0.0;
#pragma unroll 8
    for (int i = 0; i < 128; i++) {
        double2 yv = y2[i];
        double2 wv = w2[i];
        s0 = fma(wv.x, yv.x, s0);
        s1 = fma(wv.y, yv.y, s1);
    }
    dlog[gid] = s0 + s1 + bd[a];
}

// ---------------- kernel 4: exact top-1000, reg-cached keys + 8x replicated histograms ------
__global__ __launch_bounds__(1024, 1) void topk1000(
    const double* __restrict__ dlog, int* __restrict__ selidx)
{
    const int b = blockIdx.x;
    const int t = threadIdx.x;
    const double* d = dlog + (size_t)b * 36864;

    ULL key[36];                      // 36864 = 36 * 1024, coalesced; 72 VGPRs
#pragma unroll
    for (int j = 0; j < 36; j++) key[j] = fkey64(d[t + j * 1024]);

    __shared__ unsigned int hist[2048];   // 8 replicas x 256 buckets
    __shared__ ULL sh_prefix;
    __shared__ unsigned int sh_need;
    const int rep = (t >> 6) & 7;         // wave id mod 8 -> replica

    ULL prefix = 0ull;
    int need = 1000;
    for (int rs = 56; rs >= 0; rs -= 8) {
        hist[t] = 0u; hist[t + 1024] = 0u;
        __syncthreads();
        ULL mhi = (rs == 56) ? 0ull : (~0ull << (rs + 8));
#pragma unroll
        for (int j = 0; j < 36; j++) {
            ULL u = key[j];
            if ((u & mhi) == prefix)
                atomicAdd(&hist[rep * 256 + ((unsigned int)(u >> rs) & 255u)], 1u);
        }
        __syncthreads();
        if (t < 256) {                    // fold 8 replicas into replica 0
            unsigned int s = hist[t];
#pragma unroll
            for (int rr = 1; rr < 8; rr++) s += hist[rr * 256 + t];
            hist[t] = s;
        }
        __syncthreads();
        if (t == 0) {
            int cum = 0; int v = 255;
            for (; v > 0; v--) {
                int c = (int)hist[v];
                if (cum + c >= need) break;
                cum += c;
            }
            sh_prefix = prefix | ((ULL)v << rs);
            sh_need = (unsigned int)(need - cum);
        }
        __syncthreads();
        prefix = sh_prefix;
        need = (int)sh_need;
        __syncthreads();
    }

    const ULL K = prefix;                    // exact fp64 key of the 1000th largest
    const int count_above = 1000 - need;     // strictly greater than K
    __shared__ ULL skey[1024];
    __shared__ int sidx[1024];
    __shared__ unsigned int cgt, ceq;
    if (t == 0) { cgt = 0u; ceq = 0u; }
    skey[t] = ~0ull;
    sidx[t] = 0x7FFFFFFF;
    __syncthreads();
#pragma unroll
    for (int j = 0; j < 36; j++) {
        ULL u = key[j];
        int i = t + j * 1024;
        if (u > K) {
            unsigned int s = atomicAdd(&cgt, 1u);
            skey[s] = ~u; sidx[s] = i;
        } else if (u == K) {
            unsigned int s = atomicAdd(&ceq, 1u) + (unsigned int)count_above;
            if (s < 1024u) { skey[s] = ~u; sidx[s] = i; }
        }
    }
    __syncthreads();
    // bitonic sort ascending on (key, idx): == score desc, index asc on ties
    for (int k = 2; k <= 1024; k <<= 1) {
        for (int j = k >> 1; j > 0; j >>= 1) {
            int ixj = t ^ j;
            if (ixj > t) {
                ULL ka = skey[t], kb = skey[ixj];
                int ia = sidx[t], ib = sidx[ixj];
                bool up = ((t & k) == 0);
                bool gt = (ka > kb) || (ka == kb && ia > ib);
                bool lt = (ka < kb) || (ka == kb && ia < ib);
                if (up ? gt : lt) {
                    skey[t] = kb; skey[ixj] = ka;
                    sidx[t] = ib; sidx[ixj] = ia;
                }
            }
            __syncthreads();
        }
    }
    if (t < 1000) selidx[b * 1000 + t] = sidx[t];
}

// ---------------- kernel 5: reg head, wave-per-roi (coalesced y read + butterfly reduce) ----
__global__ __launch_bounds__(256) void decode_boxes2(
    const double* __restrict__ y, const int* __restrict__ selidx,
    const float* __restrict__ wregp, const float* __restrict__ bregp,
    const float* __restrict__ anchors, double4* __restrict__ boxes)
{
    __shared__ float wl[9216];
    __shared__ float bl[36];
    for (int i = threadIdx.x; i < 9216; i += 256) wl[i] = wregp[i];
    if (threadIdx.x < 36) bl[threadIdx.x] = bregp[threadIdx.x];
    __syncthreads();

    const int roi  = (blockIdx.x * 256 + threadIdx.x) >> 6;   // 0..7999
    const int lane = threadIdx.x & 63;
    const int b = roi / 1000;
    const int n = selidx[roi];                  // wave-uniform
    const int a = n % 9;
    const int pix = n / 9;

    const double2* yrow = (const double2*)(y + ((size_t)(b * 4096 + pix)) * 256);
    double2 ya = yrow[lane];
    double2 yc = yrow[lane + 64];

    double s[4];
#pragma unroll
    for (int c = 0; c < 4; c++) {
        const float* wp = wl + (4 * a + c) * 256;
        float2 wa = *(const float2*)(wp + 2 * lane);
        float2 wc = *(const float2*)(wp + 128 + 2 * lane);
        double v = 0.0;
        v = fma((double)wa.x, ya.x, v);
        v = fma((double)wa.y, ya.y, v);
        v = fma((double)wc.x, yc.x, v);
        v = fma((double)wc.y, yc.y, v);
        s[c] = v;
    }
#pragma unroll
    for (int off = 32; off > 0; off >>= 1) {
#pragma unroll
        for (int c = 0; c < 4; c++) s[c] += __shfl_xor(s[c], off);
    }

    if (lane == 0) {
        double a0 = s[0] + (double)bl[4 * a + 0];
        double a1 = s[1] + (double)bl[4 * a + 1];
        double a2 = s[2] + (double)bl[4 * a + 2];
        double a3 = s[3] + (double)bl[4 * a + 3];
        float4 an = ((const float4*)anchors)[n];
        double ax1 = an.x, ay1 = an.y, ax2 = an.z, ay2 = an.w;
        double aw = ax2 - ax1, ah = ay2 - ay1;
        double cx = 0.5 * (ax1 + ax2), cy = 0.5 * (ay1 + ay2);
        double pcx = a0 * aw + cx, pcy = a1 * ah + cy;
        double pw = exp(a2) * aw, ph = exp(a3) * ah;
        double x1b = pcx - 0.5 * pw, y1b = pcy - 0.5 * ph;
        double x2b = pcx + 0.5 * pw, y2b = pcy + 0.5 * ph;
        x1b = fmin(fmax(x1b, 0.0), 1023.0);
        y1b = fmin(fmax(y1b, 0.0), 1023.0);
        x2b = fmin(fmax(x2b, 0.0), 1023.0);
        y2b = fmin(fmax(y2b, 0.0), 1023.0);
        double4 o; o.x = x1b; o.y = y1b; o.z = x2b; o.w = y2b;
        boxes[roi] = o;
    }
}

// ---------------- kernel 6: NMS suppression bitmask matrix (fp64 IoU) -----------------------
__global__ __launch_bounds__(1024) void nms_mask_k(
    const double4* __restrict__ boxes, ULL* __restrict__ mask)
{
    int b = blockIdx.x >> 3;
    int sub = blockIdx.x & 7;
    __shared__ double4 bx[1000];
    for (int i = threadIdx.x; i < 1000; i += 1024) bx[i] = boxes[b * 1000 + i];
    __syncthreads();
    for (int ml = threadIdx.x; ml < 2000; ml += 1024) {
        int m = sub * 2000 + ml;
        int i = m >> 4;
        int wc = m & 15;
        ULL bits = 0ull;
        int j0 = wc << 6;
        if (j0 + 63 > i) {
            double4 bi = bx[i];
            double ai = (bi.z - bi.x) * (bi.w - bi.y);
            int js = max(j0, i + 1);
            int je = min(j0 + 64, 1000);
            for (int j = js; j < je; j++) {
                double4 bj = bx[j];
                double lx = fmax(bi.x, bj.x), ly = fmax(bi.y, bj.y);
                double ux = fmin(bi.z, bj.z), uy = fmin(bi.w, bj.w);
                double iw = fmax(ux - lx, 0.0), ih = fmax(uy - ly, 0.0);
                double inter = iw * ih;
                double aj = (bj.z - bj.x) * (bj.w - bj.y);
                double iou = inter / (ai + aj - inter);
                if (iou > 0.7) bits |= (1ull << (j - j0));
            }
        }
        mask[(size_t)b * 16000 + m] = bits;
    }
}

// ---------------- kernel 7: sequential greedy scan + compaction -----------------------------
// pf[] indexed ONLY by compile-time constants (r5 bug: dynamic pf[i&15] -> scratch)
__global__ __launch_bounds__(1024) void nms_scan_k(
    const ULL* __restrict__ mask, const double4* __restrict__ boxes,
    float* __restrict__ out)
{
    int b = blockIdx.x;
    int t = threadIdx.x;
    __shared__ ULL keepw[16];
    if (t < 64) {           // wave 0 only
        int lane = t;
        const ULL* mrow = mask + (size_t)b * 16000;
        ULL remv = 0ull, cur = 0ull;
        ULL pf[16];
#pragma unroll
        for (int q = 0; q < 16; q++) pf[q] = (lane < 16) ? mrow[q * 16 + lane] : 0ull;
        for (int base = 0; base < 1000; base += 16) {
#pragma unroll
            for (int q = 0; q < 16; q++) {
                int i = base + q;
                if (i < 1000) {
                    ULL m = pf[q];
                    int c = i >> 6;
                    ULL mc = __shfl(m, c);
                    bool rem = ((cur >> (i & 63)) & 1ull) != 0ull;
                    if (!rem) { remv |= m; cur |= mc; }
                    if (((i + 1) & 63) == 0) cur = __shfl(remv, (i + 1) >> 6);
                    int nx = i + 16;
                    pf[q] = (lane < 16 && nx < 1000) ? mrow[(size_t)nx * 16 + lane] : 0ull;
                }
            }
        }
        if (lane < 16) keepw[lane] = ~remv;
    }
    __syncthreads();
    if (t < 300) {
        float* row = out + (size_t)(b * 300 + t) * 5;
        row[0] = (float)b; row[1] = 0.f; row[2] = 0.f; row[3] = 0.f; row[4] = 0.f;
    }
    __syncthreads();
    if (t < 1000) {
        ULL kw = keepw[t >> 6];
        if ((kw >> (t & 63)) & 1ull) {
            int pos = (int)__popcll(kw & ((1ull << (t & 63)) - 1ull));
            for (int w = 0; w < (t >> 6); w++) pos += (int)__popcll(keepw[w]);
            if (pos < 300) {
                double4 bv = boxes[b * 1000 + t];
                float* row = out + (size_t)(b * 300 + pos) * 5;
                row[1] = (float)bv.x; row[2] = (float)bv.y;
                row[3] = (float)bv.z; row[4] = (float)bv.w;
            }
        }
    }
}

// ---------------- launcher ----------------
extern "C" void kernel_launch(void* const* d_in, const int* in_sizes, int n_in,
                              void* d_out, int out_size, void* d_ws, size_t ws_size,
                              hipStream_t stream)
{
    const float* xin     = (const float*)d_in[0];
    const float* anchors = (const float*)d_in[2];
    const float* wconv   = (const float*)d_in[3];
    const float* bconv   = (const float*)d_in[4];
    const float* wclf    = (const float*)d_in[5];
    const float* bclf    = (const float*)d_in[6];
    const float* wregp   = (const float*)d_in[7];
    const float* bregp   = (const float*)d_in[8];
    float* out = (float*)d_out;

    // ws layout (~74.2 MB; wt64's region is reused by boxes/mask/selidx after conv):
    char* base = (char*)d_ws;
    double*  y      = (double*)(base);              // 67,108,864 B  [conv out, fp64 NHWC]
    double*  wt64   = (double*)(base + 67108864);   //  4,718,592 B  [live: prep -> conv]
    double4* boxes  = (double4*)(base + 67108864);  //    256,000 B  [live: decode -> end]
    ULL*     mask   = (ULL*)(base + 67364864);      //  1,024,000 B
    int*     selidx = (int*)(base + 68388864);      //     32,000 B
    double*  dlog   = (double*)(base + 71827456);   //  2,359,296 B
    double*  wdiff  = (double*)(base + 74186752);   //     18,432 B
    double*  bdiff  = (double*)(base + 74205184);   //         72 B

    prep_all<<<2313, 256, 0, stream>>>(wconv, wclf, bclf, wt64, wdiff, bdiff);
    conv3x3_relu_f64<<<512, 256, 0, stream>>>(xin, wt64, bconv, y);
    head_clf2<<<1152, 256, 0, stream>>>(y, wdiff, bdiff, dlog);
    topk1000<<<8, 1024, 0, stream>>>(dlog, selidx);
    decode_boxes2<<<2000, 256, 0, stream>>>(y, selidx, wregp, bregp, anchors, boxes);
    nms_mask_k<<<64, 1024, 0, stream>>>(boxes, mask);
    nms_scan_k<<<8, 1024, 0, stream>>>(mask, boxes, out);
}

// Round 11
// 1239.140 us; speedup vs baseline: 1.0770x; 1.0770x over previous
//
#include <hip/hip_runtime.h>

typedef unsigned long long ULL;

// B=8, Cin=Cout=256, H=W=64, A=9, N=36864/batch, PRE=1000, POST=300

__device__ __forceinline__ ULL fkey64(double f) {
    ULL u = (ULL)__double_as_longlong(f);
    return (u & 0x8000000000000000ull) ? ~u : (u | 0x8000000000000000ull);
}

// ---------------- kernel 1: prep (merged): wt64 transpose->fp64 + clf diff weights ----------
__global__ void prep_all(const float* __restrict__ wconv,
                         const float* __restrict__ wclf, const float* __restrict__ bclf,
                         double* __restrict__ wt64,
                         double* __restrict__ wdiff, double* __restrict__ bdiff) {
    int blk = blockIdx.x;
    if (blk < 2304) {
        int e = blk * 256 + threadIdx.x;   // 589824 total
        int row = e >> 8;                  // ci*9 + tap
        int co = e & 255;
        int ci = row / 9;
        int tap = row - ci * 9;
        wt64[e] = (double)wconv[(co * 256 + ci) * 9 + tap];
    } else {
        int a = blk - 2304;                // 0..8
        int c = threadIdx.x;
        wdiff[a * 256 + c] = (double)wclf[(9 + a) * 256 + c] - (double)wclf[a * 256 + c];
        if (c == 0) bdiff[a] = (double)bclf[9 + a] - (double)bclf[a];
    }
}

// ---------------- kernel 2: 3x3 conv + bias + relu, fp64 dfma, 8px x 8co per thread ---------
// Byte-identical math to r10 (correctness-proven). Allocation fix: r4/r10 showed the
// register allocator targets a HIGHER occupancy level than __launch_bounds__' minimum and
// spills acc to scratch (r10: VGPR=112, WRITE_SIZE=636MB). amdgpu_waves_per_eu(2,2) pins
// max=min=2 waves/EU so there is no occupancy incentive -> acc[8][8] (128 VGPR) + wreg (36)
// allocate in the 256-VGPR budget with zero spill.
__global__ __launch_bounds__(256)
__attribute__((amdgpu_waves_per_eu(2, 2)))
void conv3x3_relu_f64(
    const float* __restrict__ xin, const double* __restrict__ wt64,
    const float* __restrict__ bias, double* __restrict__ y)
{
    __shared__ double wsd[4608];   // [k 0..35][co 0..127] for this cog (d2 idx = k*64+c2)
    __shared__ float xs[1152];     // [cil 0..3][row 0..3][72]; col c holds input col c-1

    const int t = threadIdx.x;
    const int blk = blockIdx.x;
    const int b = blk >> 6;
    const int rp = (blk >> 1) & 31;
    const int cog = blk & 1;
    const int h0 = rp * 2;
    const int tx = t & 15, ty = t >> 4;
    const int r = tx >> 3;                 // output row within pair
    const int colbase = (tx & 7) * 8;      // 8 consecutive output cols

    double acc[8][8];                      // [co][px]
#pragma unroll
    for (int i = 0; i < 8; i++)
#pragma unroll
        for (int j = 0; j < 8; j++) acc[i][j] = 0.0;

    // x staging decomposition: 4 cil * 4 rows (h0-1..h0+2) * 66 cols = 1056 elems
    int x_ld[5], x_go[5];
#pragma unroll
    for (int i = 0; i < 5; i++) {
        int e = t + i * 256;
        x_ld[i] = -1; x_go[i] = -1;
        if (e < 1056) {
            int cil = e / 264; int rem = e - cil * 264;
            int row = rem / 66; int c = rem - row * 66;
            int hh = h0 - 1 + row; int col = c - 1;
            x_ld[i] = (cil * 4 + row) * 72 + c;
            if (hh >= 0 && hh < 64 && col >= 0 && col < 64)
                x_go[i] = cil * 4096 + hh * 64 + col;
        }
    }
    // w: 2304 double2 per chunk; e2 = t + i*256; k = e2>>6, c2 = e2&63
    // global d2 (chunk-rel) = k*128 + cog*64 + c2 = e2 + (e2>>6)*64 + cog*64
    int w_g[9];
#pragma unroll
    for (int i = 0; i < 9; i++) {
        int e2 = t + i * 256;
        w_g[i] = e2 + (e2 >> 6) * 64 + cog * 64;
    }

    const float* xb = xin + (size_t)b * 1048576;
    const double2* wt2 = (const double2*)wt64;
    double2* wsd2 = (double2*)wsd;

    // preload chunk 0 into regs
    float xreg[5];
    double2 wreg[9];
#pragma unroll
    for (int i = 0; i < 5; i++)
        xreg[i] = (x_ld[i] >= 0 && x_go[i] >= 0) ? xb[x_go[i]] : 0.f;
#pragma unroll
    for (int i = 0; i < 9; i++) wreg[i] = wt2[w_g[i]];

    for (int cc = 0; cc < 64; ++cc) {
        __syncthreads();   // previous compute done before LDS overwrite
#pragma unroll
        for (int i = 0; i < 5; i++) if (x_ld[i] >= 0) xs[x_ld[i]] = xreg[i];
#pragma unroll
        for (int i = 0; i < 9; i++) wsd2[t + i * 256] = wreg[i];
        __syncthreads();

        // prefetch next chunk into regs (overlaps with compute below)
        if (cc < 63) {
#pragma unroll
            for (int i = 0; i < 5; i++)
                if (x_ld[i] >= 0)
                    xreg[i] = (x_go[i] >= 0) ? xb[(cc + 1) * 16384 + x_go[i]] : 0.f;
#pragma unroll
            for (int i = 0; i < 9; i++)
                wreg[i] = wt2[(size_t)(cc + 1) * 4608 + w_g[i]];
        }

#pragma unroll
        for (int cil = 0; cil < 4; cil++) {
#pragma unroll
            for (int kh = 0; kh < 3; kh++) {
                const float* xrow = &xs[(cil * 4 + r + kh) * 72 + colbase];
                float4 xa = *(const float4*)xrow;
                float4 xb4 = *(const float4*)(xrow + 4);
                float2 xc2 = *(const float2*)(xrow + 8);
                double xd[10] = { (double)xa.x, (double)xa.y, (double)xa.z, (double)xa.w,
                                  (double)xb4.x, (double)xb4.y, (double)xb4.z, (double)xb4.w,
                                  (double)xc2.x, (double)xc2.y };
#pragma unroll
                for (int kw = 0; kw < 3; kw++) {
                    int k = cil * 9 + kh * 3 + kw;
                    const double2* wp = (const double2*)wsd + (k * 64 + ty * 4);
                    double2 w01 = wp[0], w23 = wp[1], w45 = wp[2], w67 = wp[3];
#pragma unroll
                    for (int j = 0; j < 8; j++) {
                        double xv = xd[j + kw];
                        acc[0][j] = fma(w01.x, xv, acc[0][j]);
                        acc[1][j] = fma(w01.y, xv, acc[1][j]);
                        acc[2][j] = fma(w23.x, xv, acc[2][j]);
                        acc[3][j] = fma(w23.y, xv, acc[3][j]);
                        acc[4][j] = fma(w45.x, xv, acc[4][j]);
                        acc[5][j] = fma(w45.y, xv, acc[5][j]);
                        acc[6][j] = fma(w67.x, xv, acc[6][j]);
                        acc[7][j] = fma(w67.y, xv, acc[7][j]);
                    }
                }
            }
        }
    }

    // epilogue: bias + relu (fp64), store NHWC fp64
    const float* bptr = bias + cog * 128 + ty * 8;
    double bs[8];
#pragma unroll
    for (int i = 0; i < 8; i++) bs[i] = (double)bptr[i];
    const int h = h0 + r;
    double* yb = y + ((size_t)(b * 4096 + h * 64 + colbase)) * 256 + cog * 128 + ty * 8;
#pragma unroll
    for (int j = 0; j < 8; j++) {
        double4 o0, o1;
        o0.x = fmax(acc[0][j] + bs[0], 0.0);
        o0.y = fmax(acc[1][j] + bs[1], 0.0);
        o0.z = fmax(acc[2][j] + bs[2], 0.0);
        o0.w = fmax(acc[3][j] + bs[3], 0.0);
        o1.x = fmax(acc[4][j] + bs[4], 0.0);
        o1.y = fmax(acc[5][j] + bs[5], 0.0);
        o1.z = fmax(acc[6][j] + bs[6], 0.0);
        o1.w = fmax(acc[7][j] + bs[7], 0.0);
        double* yp = yb + (size_t)j * 256;
        *(double4*)yp = o0;
        *((double4*)yp + 1) = o1;
    }
}

// ---------------- kernel 3: clf head via fp64 diff-weights; thread = (pixel, anchor) ---------
__global__ __launch_bounds__(256) void head_clf2(
    const double* __restrict__ y, const double* __restrict__ wdiff,
    const double* __restrict__ bdiff, double* __restrict__ dlog)
{
    __shared__ double wd[9 * 258];   // padded stride 258 (bank spread)
    __shared__ double bd[9];
    for (int i = threadIdx.x; i < 9 * 258; i += 256) {
        int a = i / 258, c = i - a * 258;
        wd[i] = (c < 256) ? wdiff[a * 256 + c] : 0.0;
    }
    if (threadIdx.x < 9) bd[threadIdx.x] = bdiff[threadIdx.x];
    __syncthreads();

    int gid = blockIdx.x * 256 + threadIdx.x;    // 0..294911
    int px = gid / 9;
    int a = gid - px * 9;
    const double2* y2 = (const double2*)(y + (size_t)px * 256);
    const double2* w2 = (const double2*)(wd + a * 258);
    double s0 = 0.0, s1 = 0.0;
#pragma unroll 8
    for (int i = 0; i < 128; i++) {
        double2 yv = y2[i];
        double2 wv = w2[i];
        s0 = fma(wv.x, yv.x, s0);
        s1 = fma(wv.y, yv.y, s1);
    }
    dlog[gid] = s0 + s1 + bd[a];
}

// ---------------- kernel 4: exact top-1000, reg-cached keys + 8x replicated histograms ------
__global__ __launch_bounds__(1024, 1) void topk1000(
    const double* __restrict__ dlog, int* __restrict__ selidx)
{
    const int b = blockIdx.x;
    const int t = threadIdx.x;
    const double* d = dlog + (size_t)b * 36864;

    ULL key[36];                      // 36864 = 36 * 1024, coalesced; 72 VGPRs
#pragma unroll
    for (int j = 0; j < 36; j++) key[j] = fkey64(d[t + j * 1024]);

    __shared__ unsigned int hist[2048];   // 8 replicas x 256 buckets
    __shared__ ULL sh_prefix;
    __shared__ unsigned int sh_need;
    const int rep = (t >> 6) & 7;         // wave id mod 8 -> replica

    ULL prefix = 0ull;
    int need = 1000;
    for (int rs = 56; rs >= 0; rs -= 8) {
        hist[t] = 0u; hist[t + 1024] = 0u;
        __syncthreads();
        ULL mhi = (rs == 56) ? 0ull : (~0ull << (rs + 8));
#pragma unroll
        for (int j = 0; j < 36; j++) {
            ULL u = key[j];
            if ((u & mhi) == prefix)
                atomicAdd(&hist[rep * 256 + ((unsigned int)(u >> rs) & 255u)], 1u);
        }
        __syncthreads();
        if (t < 256) {                    // fold 8 replicas into replica 0
            unsigned int s = hist[t];
#pragma unroll
            for (int rr = 1; rr < 8; rr++) s += hist[rr * 256 + t];
            hist[t] = s;
        }
        __syncthreads();
        if (t == 0) {
            int cum = 0; int v = 255;
            for (; v > 0; v--) {
                int c = (int)hist[v];
                if (cum + c >= need) break;
                cum += c;
            }
            sh_prefix = prefix | ((ULL)v << rs);
            sh_need = (unsigned int)(need - cum);
        }
        __syncthreads();
        prefix = sh_prefix;
        need = (int)sh_need;
        __syncthreads();
    }

    const ULL K = prefix;                    // exact fp64 key of the 1000th largest
    const int count_above = 1000 - need;     // strictly greater than K
    __shared__ ULL skey[1024];
    __shared__ int sidx[1024];
    __shared__ unsigned int cgt, ceq;
    if (t == 0) { cgt = 0u; ceq = 0u; }
    skey[t] = ~0ull;
    sidx[t] = 0x7FFFFFFF;
    __syncthreads();
#pragma unroll
    for (int j = 0; j < 36; j++) {
        ULL u = key[j];
        int i = t + j * 1024;
        if (u > K) {
            unsigned int s = atomicAdd(&cgt, 1u);
            skey[s] = ~u; sidx[s] = i;
        } else if (u == K) {
            unsigned int s = atomicAdd(&ceq, 1u) + (unsigned int)count_above;
            if (s < 1024u) { skey[s] = ~u; sidx[s] = i; }
        }
    }
    __syncthreads();
    // bitonic sort ascending on (key, idx): == score desc, index asc on ties
    for (int k = 2; k <= 1024; k <<= 1) {
        for (int j = k >> 1; j > 0; j >>= 1) {
            int ixj = t ^ j;
            if (ixj > t) {
                ULL ka = skey[t], kb = skey[ixj];
                int ia = sidx[t], ib = sidx[ixj];
                bool up = ((t & k) == 0);
                bool gt = (ka > kb) || (ka == kb && ia > ib);
                bool lt = (ka < kb) || (ka == kb && ia < ib);
                if (up ? gt : lt) {
                    skey[t] = kb; skey[ixj] = ka;
                    sidx[t] = ib; sidx[ixj] = ia;
                }
            }
            __syncthreads();
        }
    }
    if (t < 1000) selidx[b * 1000 + t] = sidx[t];
}

// ---------------- kernel 5: reg head, wave-per-roi (coalesced y read + butterfly reduce) ----
__global__ __launch_bounds__(256) void decode_boxes2(
    const double* __restrict__ y, const int* __restrict__ selidx,
    const float* __restrict__ wregp, const float* __restrict__ bregp,
    const float* __restrict__ anchors, double4* __restrict__ boxes)
{
    __shared__ float wl[9216];
    __shared__ float bl[36];
    for (int i = threadIdx.x; i < 9216; i += 256) wl[i] = wregp[i];
    if (threadIdx.x < 36) bl[threadIdx.x] = bregp[threadIdx.x];
    __syncthreads();

    const int roi  = (blockIdx.x * 256 + threadIdx.x) >> 6;   // 0..7999
    const int lane = threadIdx.x & 63;
    const int b = roi / 1000;
    const int n = selidx[roi];                  // wave-uniform
    const int a = n % 9;
    const int pix = n / 9;

    const double2* yrow = (const double2*)(y + ((size_t)(b * 4096 + pix)) * 256);
    double2 ya = yrow[lane];
    double2 yc = yrow[lane + 64];

    double s[4];
#pragma unroll
    for (int c = 0; c < 4; c++) {
        const float* wp = wl + (4 * a + c) * 256;
        float2 wa = *(const float2*)(wp + 2 * lane);
        float2 wc = *(const float2*)(wp + 128 + 2 * lane);
        double v = 0.0;
        v = fma((double)wa.x, ya.x, v);
        v = fma((double)wa.y, ya.y, v);
        v = fma((double)wc.x, yc.x, v);
        v = fma((double)wc.y, yc.y, v);
        s[c] = v;
    }
#pragma unroll
    for (int off = 32; off > 0; off >>= 1) {
#pragma unroll
        for (int c = 0; c < 4; c++) s[c] += __shfl_xor(s[c], off);
    }

    if (lane == 0) {
        double a0 = s[0] + (double)bl[4 * a + 0];
        double a1 = s[1] + (double)bl[4 * a + 1];
        double a2 = s[2] + (double)bl[4 * a + 2];
        double a3 = s[3] + (double)bl[4 * a + 3];
        float4 an = ((const float4*)anchors)[n];
        double ax1 = an.x, ay1 = an.y, ax2 = an.z, ay2 = an.w;
        double aw = ax2 - ax1, ah = ay2 - ay1;
        double cx = 0.5 * (ax1 + ax2), cy = 0.5 * (ay1 + ay2);
        double pcx = a0 * aw + cx, pcy = a1 * ah + cy;
        double pw = exp(a2) * aw, ph = exp(a3) * ah;
        double x1b = pcx - 0.5 * pw, y1b = pcy - 0.5 * ph;
        double x2b = pcx + 0.5 * pw, y2b = pcy + 0.5 * ph;
        x1b = fmin(fmax(x1b, 0.0), 1023.0);
        y1b = fmin(fmax(y1b, 0.0), 1023.0);
        x2b = fmin(fmax(x2b, 0.0), 1023.0);
        y2b = fmin(fmax(y2b, 0.0), 1023.0);
        double4 o; o.x = x1b; o.y = y1b; o.z = x2b; o.w = y2b;
        boxes[roi] = o;
    }
}

// ---------------- kernel 6: NMS suppression bitmask matrix (fp64 IoU) -----------------------
__global__ __launch_bounds__(1024) void nms_mask_k(
    const double4* __restrict__ boxes, ULL* __restrict__ mask)
{
    int b = blockIdx.x >> 3;
    int sub = blockIdx.x & 7;
    __shared__ double4 bx[1000];
    for (int i = threadIdx.x; i < 1000; i += 1024) bx[i] = boxes[b * 1000 + i];
    __syncthreads();
    for (int ml = threadIdx.x; ml < 2000; ml += 1024) {
        int m = sub * 2000 + ml;
        int i = m >> 4;
        int wc = m & 15;
        ULL bits = 0ull;
        int j0 = wc << 6;
        if (j0 + 63 > i) {
            double4 bi = bx[i];
            double ai = (bi.z - bi.x) * (bi.w - bi.y);
            int js = max(j0, i + 1);
            int je = min(j0 + 64, 1000);
            for (int j = js; j < je; j++) {
                double4 bj = bx[j];
                double lx = fmax(bi.x, bj.x), ly = fmax(bi.y, bj.y);
                double ux = fmin(bi.z, bj.z), uy = fmin(bi.w, bj.w);
                double iw = fmax(ux - lx, 0.0), ih = fmax(uy - ly, 0.0);
                double inter = iw * ih;
                double aj = (bj.z - bj.x) * (bj.w - bj.y);
                double iou = inter / (ai + aj - inter);
                if (iou > 0.7) bits |= (1ull << (j - j0));
            }
        }
        mask[(size_t)b * 16000 + m] = bits;
    }
}

// ---------------- kernel 7: sequential greedy scan + compaction -----------------------------
// pf[] indexed ONLY by compile-time constants (r5 bug: dynamic pf[i&15] -> scratch)
__global__ __launch_bounds__(1024) void nms_scan_k(
    const ULL* __restrict__ mask, const double4* __restrict__ boxes,
    float* __restrict__ out)
{
    int b = blockIdx.x;
    int t = threadIdx.x;
    __shared__ ULL keepw[16];
    if (t < 64) {           // wave 0 only
        int lane = t;
        const ULL* mrow = mask + (size_t)b * 16000;
        ULL remv = 0ull, cur = 0ull;
        ULL pf[16];
#pragma unroll
        for (int q = 0; q < 16; q++) pf[q] = (lane < 16) ? mrow[q * 16 + lane] : 0ull;
        for (int base = 0; base < 1000; base += 16) {
#pragma unroll
            for (int q = 0; q < 16; q++) {
                int i = base + q;
                if (i < 1000) {
                    ULL m = pf[q];
                    int c = i >> 6;
                    ULL mc = __shfl(m, c);
                    bool rem = ((cur >> (i & 63)) & 1ull) != 0ull;
                    if (!rem) { remv |= m; cur |= mc; }
                    if (((i + 1) & 63) == 0) cur = __shfl(remv, (i + 1) >> 6);
                    int nx = i + 16;
                    pf[q] = (lane < 16 && nx < 1000) ? mrow[(size_t)nx * 16 + lane] : 0ull;
                }
            }
        }
        if (lane < 16) keepw[lane] = ~remv;
    }
    __syncthreads();
    if (t < 300) {
        float* row = out + (size_t)(b * 300 + t) * 5;
        row[0] = (float)b; row[1] = 0.f; row[2] = 0.f; row[3] = 0.f; row[4] = 0.f;
    }
    __syncthreads();
    if (t < 1000) {
        ULL kw = keepw[t >> 6];
        if ((kw >> (t & 63)) & 1ull) {
            int pos = (int)__popcll(kw & ((1ull << (t & 63)) - 1ull));
            for (int w = 0; w < (t >> 6); w++) pos += (int)__popcll(keepw[w]);
            if (pos < 300) {
                double4 bv = boxes[b * 1000 + t];
                float* row = out + (size_t)(b * 300 + pos) * 5;
                row[1] = (float)bv.x; row[2] = (float)bv.y;
                row[3] = (float)bv.z; row[4] = (float)bv.w;
            }
        }
    }
}

// ---------------- launcher ----------------
extern "C" void kernel_launch(void* const* d_in, const int* in_sizes, int n_in,
                              void* d_out, int out_size, void* d_ws, size_t ws_size,
                              hipStream_t stream)
{
    const float* xin     = (const float*)d_in[0];
    const float* anchors = (const float*)d_in[2];
    const float* wconv   = (const float*)d_in[3];
    const float* bconv   = (const float*)d_in[4];
    const float* wclf    = (const float*)d_in[5];
    const float* bclf    = (const float*)d_in[6];
    const float* wregp   = (const float*)d_in[7];
    const float* bregp   = (const float*)d_in[8];
    float* out = (float*)d_out;

    // ws layout (~74.2 MB; wt64's region is reused by boxes/mask/selidx after conv):
    char* base = (char*)d_ws;
    double*  y      = (double*)(base);              // 67,108,864 B  [conv out, fp64 NHWC]
    double*  wt64   = (double*)(base + 67108864);   //  4,718,592 B  [live: prep -> conv]
    double4* boxes  = (double4*)(base + 67108864);  //    256,000 B  [live: decode -> end]
    ULL*     mask   = (ULL*)(base + 67364864);      //  1,024,000 B
    int*     selidx = (int*)(base + 68388864);      //     32,000 B
    double*  dlog   = (double*)(base + 71827456);   //  2,359,296 B
    double*  wdiff  = (double*)(base + 74186752);   //     18,432 B
    double*  bdiff  = (double*)(base + 74205184);   //         72 B

    prep_all<<<2313, 256, 0, stream>>>(wconv, wclf, bclf, wt64, wdiff, bdiff);
    conv3x3_relu_f64<<<512, 256, 0, stream>>>(xin, wt64, bconv, y);
    head_clf2<<<1152, 256, 0, stream>>>(y, wdiff, bdiff, dlog);
    topk1000<<<8, 1024, 0, stream>>>(dlog, selidx);
    decode_boxes2<<<2000, 256, 0, stream>>>(y, selidx, wregp, bregp, anchors, boxes);
    nms_mask_k<<<64, 1024, 0, stream>>>(boxes, mask);
    nms_scan_k<<<8, 1024, 0, stream>>>(mask, boxes, out);
}